// Round 1
// 164.739 us; speedup vs baseline: 1.0843x; 1.0843x over previous
//
#include <hip/hip_runtime.h>
#include <hip/hip_fp16.h>

// Problem constants (from reference): N=50000, E=800000, dims 128->128->64->2.
#define IN_DIM 128
#define HID_DIM 128
#define OUT_DIM 64
#define BINW 128          // nodes per bin (dst >> 7)
#define BINSHIFT 7
#define MAXBIN 512        // LDS bound; nbin = ceil(N/128) = 391 for N=50000
#define CAP 4096          // fixed bin capacity (mean 2046; overflow handled correctly)
#define CNTSTRIDE 16      // bin_cnt stride in ints (one 64B line per counter)
#define SC_GRID 256       // scatter sub-grid (logical), fused into k_build_gemm

// ---------------- fused K1: [gemm1 tiles | scatter blocks] ----------------
// gemm1 no longer pre-scales by dinv (deferred to k_agg1z as per-edge FMA
// weight), so it has NO dependency on the CSR build -> co-schedule both.
// gemm tiles are FMA-pipe-bound; scatter blocks are latency/LDS-atomic-bound
// with near-idle VALU. Co-residency (3 blk/CU, 647 blocks total) overlaps them.
__global__ __launch_bounds__(256) void k_build_gemm(const float* __restrict__ x,
                                                    const float* __restrict__ W,
                                                    __half* __restrict__ xwh,
                                                    const int* __restrict__ src,
                                                    const int* __restrict__ dst,
                                                    int* __restrict__ bin_cnt,   // stride CNTSTRIDE
                                                    int* __restrict__ ovf_cnt,
                                                    unsigned int* __restrict__ ovf,
                                                    unsigned int* __restrict__ ebin,
                                                    int N, int E, int nbin) {
    __shared__ union SMem {
        float Ws[64][128];                               // gemm path: 32KB half-K W tile
        struct { int h[MAXBIN]; int base_s[MAXBIN]; } sc; // scatter path: 4KB
    } smem;
    const int nGemm = (N + 127) >> 7;
    int tid = threadIdx.x;

    if ((int)blockIdx.x < nGemm) {
        // ---------------- GEMM path: xwh = fp16(x @ W1), tile 128x128 ----------------
        float4* Ws4 = (float4*)&smem.Ws[0][0];
        int tx = tid & 15, ty = tid >> 4;
        int row0 = blockIdx.x * 128;
        int rows[8];
        const float* xr[8];
#pragma unroll
        for (int j = 0; j < 8; ++j) {
            int row = row0 + ty + 16 * j;
            rows[j] = row;
            if (row > N - 1) row = N - 1;
            xr[j] = x + (size_t)row * IN_DIM;
        }
        float4 aclo[8], achi[8];
#pragma unroll
        for (int j = 0; j < 8; ++j) {
            aclo[j] = make_float4(0.f, 0.f, 0.f, 0.f);
            achi[j] = make_float4(0.f, 0.f, 0.f, 0.f);
        }
#pragma unroll
        for (int ph = 0; ph < 2; ++ph) {
            const float4* W4 = (const float4*)(W + (size_t)ph * 64 * HID_DIM);
#pragma unroll
            for (int i = 0; i < 8; ++i) Ws4[tid + 256 * i] = W4[tid + 256 * i];
            __syncthreads();
#pragma unroll 2
            for (int k4 = 0; k4 < 16; ++k4) {
                float4 av[8];
#pragma unroll
                for (int j = 0; j < 8; ++j) av[j] = *(const float4*)(xr[j] + ph * 64 + k4 * 4);
#pragma unroll
                for (int kk = 0; kk < 4; ++kk) {
                    float4 blo = *(const float4*)&smem.Ws[k4 * 4 + kk][4 * tx];
                    float4 bhi = *(const float4*)&smem.Ws[k4 * 4 + kk][64 + 4 * tx];
#pragma unroll
                    for (int j = 0; j < 8; ++j) {
                        float a = (kk == 0) ? av[j].x : (kk == 1) ? av[j].y : (kk == 2) ? av[j].z : av[j].w;
                        aclo[j].x += a * blo.x; aclo[j].y += a * blo.y;
                        aclo[j].z += a * blo.z; aclo[j].w += a * blo.w;
                        achi[j].x += a * bhi.x; achi[j].y += a * bhi.y;
                        achi[j].z += a * bhi.z; achi[j].w += a * bhi.w;
                    }
                }
            }
            __syncthreads();
        }
#pragma unroll
        for (int j = 0; j < 8; ++j) {
            if (rows[j] < N) {
                union { __half2 h[2]; uint2 u; } lo, hi;
                lo.h[0] = __floats2half2_rn(aclo[j].x, aclo[j].y);
                lo.h[1] = __floats2half2_rn(aclo[j].z, aclo[j].w);
                hi.h[0] = __floats2half2_rn(achi[j].x, achi[j].y);
                hi.h[1] = __floats2half2_rn(achi[j].z, achi[j].w);
                uint2* p = (uint2*)(xwh + (size_t)rows[j] * HID_DIM);
                p[tx] = lo.u;
                p[16 + tx] = hi.u;
            }
        }
    } else {
        // ---------------- scatter path: hist + atomic reserve + scatter into bins ----------------
        int sb = blockIdx.x - nGemm;               // logical scatter block in [0, SC_GRID)
        int* h = smem.sc.h;
        int* base_s = smem.sc.base_s;
        for (int k = tid; k < nbin; k += 256) h[k] = 0;
        __syncthreads();
        int per = E / SC_GRID;
        int ebeg = sb * per;
        int eend = (sb + 1 == SC_GRID) ? E : ebeg + per;
        for (int i = ebeg + tid; i < eend; i += 256)
            atomicAdd(&h[dst[i] >> BINSHIFT], 1);
        __syncthreads();
        for (int k = tid; k < nbin; k += 256) {
            int c = h[k];
            base_s[k] = (c > 0) ? atomicAdd(&bin_cnt[k * CNTSTRIDE], c) : 0;
            h[k] = 0;   // reuse as local fill counter
        }
        __syncthreads();
        for (int i = ebeg + tid; i < eend; i += 256) {
            unsigned int s = (unsigned int)src[i];
            unsigned int d = (unsigned int)dst[i];
            int b = (int)(d >> BINSHIFT);
            int pos = base_s[b] + atomicAdd(&h[b], 1);
            unsigned int packed = s | (d << 16);
            if (pos < CAP) ebin[(size_t)b * CAP + pos] = packed;
            else ovf[atomicAdd(ovf_cnt, 1)] = packed;   // ovf sized E: can never drop
        }
    }
}

// ---------------- build pass 2: per-bin fill — row_ptr, deg, dinv, csr_src (u16) ----------------
// Block 0 additionally computes Wc = W2@Wfc and bc = b2@Wfc + bfc.
__global__ __launch_bounds__(256) void k_fill(const unsigned int* __restrict__ ebin,
                                              const int* __restrict__ bin_cnt,
                                              const int* __restrict__ ovf_cnt,
                                              const unsigned int* __restrict__ ovf,
                                              int* __restrict__ row_ptr,
                                              unsigned short* __restrict__ degu,
                                              unsigned short* __restrict__ csr_src,
                                              float* __restrict__ dinv,
                                              const float* __restrict__ W2,
                                              const float* __restrict__ Wfc,
                                              const float* __restrict__ b2,
                                              const float* __restrict__ bfc,
                                              float* __restrict__ Wc,
                                              float* __restrict__ bc,
                                              int N, int nbin) {
    __shared__ int cnt[BINW];
    __shared__ int excl[BINW];
    __shared__ int start[BINW];
    int k = blockIdx.x;
    int node0 = k * BINW;
    int nn = min(BINW, N - node0);
    int t = threadIdx.x;
    if (t < BINW) cnt[t] = 0;
    __syncthreads();
    int cnt_k = min(bin_cnt[k * CNTSTRIDE], CAP);
    const unsigned int* seg = ebin + (size_t)k * CAP;
    for (int i = t; i < cnt_k; i += 256)
        atomicAdd(&cnt[(seg[i] >> 16) & (BINW - 1)], 1);
    int novf = *ovf_cnt;
    for (int i = t; i < novf; i += 256) {
        unsigned int e = ovf[i];
        if ((int)(e >> (16 + BINSHIFT)) == k)
            atomicAdd(&cnt[(e >> 16) & (BINW - 1)], 1);
    }
    __syncthreads();
    if (t < BINW) excl[t] = (t < nn) ? cnt[t] : 0;
    __syncthreads();
    for (int off = 1; off < BINW; off <<= 1) {
        int u = 0;
        if (t < BINW && t >= off) u = excl[t - off];
        __syncthreads();
        if (t < BINW) excl[t] += u;   // inclusive scan
        __syncthreads();
    }
    if (t < nn) {
        int deg = cnt[t];
        int e0 = k * CAP + excl[t] - deg;   // absolute slot in csr_src (bins have holes)
        start[t] = e0;
        row_ptr[node0 + t] = e0;
        degu[node0 + t] = (unsigned short)deg;
        dinv[node0 + t] = rsqrtf((float)deg + 1.0f);
        cnt[t] = 0;                         // reuse as fill counter
    }
    __syncthreads();
    for (int i = t; i < cnt_k; i += 256) {
        unsigned int e = seg[i];
        int dl = (e >> 16) & (BINW - 1);
        int slot = start[dl] + atomicAdd(&cnt[dl], 1);
        csr_src[slot] = (unsigned short)(e & 0xffffu);
    }
    for (int i = t; i < novf; i += 256) {
        unsigned int e = ovf[i];
        if ((int)(e >> (16 + BINSHIFT)) == k) {
            int dl = (e >> 16) & (BINW - 1);
            int slot = start[dl] + atomicAdd(&cnt[dl], 1);
            csr_src[slot] = (unsigned short)(e & 0xffffu);
        }
    }
    // ---- block 0: fold Wc = W2 @ Wfc (128x2), bc = b2 @ Wfc + bfc ----
    if (k == 0) {
        int kk = t >> 1, j = t & 1;
        float acc = 0.f;
#pragma unroll 8
        for (int m = 0; m < OUT_DIM; ++m) acc += W2[kk * OUT_DIM + m] * Wfc[m * 2 + j];
        Wc[kk * 2 + j] = acc;
        if (kk == 0) {
            float b = 0.f;
#pragma unroll 8
            for (int m = 0; m < OUT_DIM; ++m) b += b2[m] * Wfc[m * 2 + j];
            bc[j] = b + bfc[j];
        }
    }
}

// ---------------- Layer-1 aggregation + bias + ReLU + (h1 @ Wc) epilogue ----------------
// xwh is now UNSCALED; per-edge weight dinv[s] applied here as FMA (same VALU
// rate as the old add). dinv is 200KB -> L2-resident; 16 lanes/edge read the
// same address -> broadcast load.
// h1 = relu(dinv[d]*(sum_s dinv[s]*xwh[s] + dinv[d]*xwh[d]) + b1)
// z[d] = dinv[d] * (h1 @ Wc).  4x-unrolled gather: 16 outstanding uint4 per wave.
__global__ __launch_bounds__(256) void k_agg1z(const int* __restrict__ row_ptr,
                                               const unsigned short* __restrict__ degu,
                                               const unsigned short* __restrict__ csr_src,
                                               const float* __restrict__ dinv,
                                               const __half* __restrict__ xwh,
                                               const float* __restrict__ b1,
                                               const float* __restrict__ Wc,
                                               float* __restrict__ z, int N) {
    constexpr int F = HID_DIM;
    constexpr int L = F / 8;       // 16 lanes per row, 16B/lane
    constexpr int EPW = 64 / L;    // 4 edge slots per wave
    __shared__ float Wcs[HID_DIM * 2];
    int tid = threadIdx.x;
    if (tid < 64) ((float4*)Wcs)[tid] = ((const float4*)Wc)[tid];
    __syncthreads();
    int node = (blockIdx.x * 256 + tid) >> 6;
    if (node >= N) return;
    int lane = tid & 63;
    int sub = lane / L;
    int c   = lane % L;
    int beg = row_ptr[node];
    int end = beg + degu[node];
    // hoisted loads (overlap with gather)
    float dd = dinv[node];
    uint4 us = *(const uint4*)(xwh + (size_t)node * F + c * 8);
    float4 b1a = *(const float4*)(b1 + c * 8);
    float4 b1b = *(const float4*)(b1 + c * 8 + 4);
    float a0 = 0.f, a1 = 0.f, a2 = 0.f, a3 = 0.f;
    float a4 = 0.f, a5 = 0.f, a6 = 0.f, a7 = 0.f;
    auto acc = [&](uint4 u, float w) {
        float2 v0 = __half22float2(*(__half2*)&u.x);
        float2 v1 = __half22float2(*(__half2*)&u.y);
        float2 v2 = __half22float2(*(__half2*)&u.z);
        float2 v3 = __half22float2(*(__half2*)&u.w);
        a0 = fmaf(v0.x, w, a0); a1 = fmaf(v0.y, w, a1);
        a2 = fmaf(v1.x, w, a2); a3 = fmaf(v1.y, w, a3);
        a4 = fmaf(v2.x, w, a4); a5 = fmaf(v2.y, w, a5);
        a6 = fmaf(v3.x, w, a6); a7 = fmaf(v3.y, w, a7);
    };
    int j = beg + sub;
    for (; j + 3 * EPW < end; j += 4 * EPW) {
        int s0 = csr_src[j];
        int s1 = csr_src[j + EPW];
        int s2 = csr_src[j + 2 * EPW];
        int s3 = csr_src[j + 3 * EPW];
        uint4 u0 = *(const uint4*)(xwh + (size_t)s0 * F + c * 8);
        uint4 u1 = *(const uint4*)(xwh + (size_t)s1 * F + c * 8);
        uint4 u2 = *(const uint4*)(xwh + (size_t)s2 * F + c * 8);
        uint4 u3 = *(const uint4*)(xwh + (size_t)s3 * F + c * 8);
        float w0 = dinv[s0];
        float w1 = dinv[s1];
        float w2 = dinv[s2];
        float w3 = dinv[s3];
        acc(u0, w0); acc(u1, w1); acc(u2, w2); acc(u3, w3);
    }
    for (; j < end; j += EPW) {
        int s = csr_src[j];
        uint4 u = *(const uint4*)(xwh + (size_t)s * F + c * 8);
        acc(u, dinv[s]);
    }
#pragma unroll
    for (int off = L; off < 64; off <<= 1) {
        a0 += __shfl_xor(a0, off); a1 += __shfl_xor(a1, off);
        a2 += __shfl_xor(a2, off); a3 += __shfl_xor(a3, off);
        a4 += __shfl_xor(a4, off); a5 += __shfl_xor(a5, off);
        a6 += __shfl_xor(a6, off); a7 += __shfl_xor(a7, off);
    }
    // all lanes now hold the full column sums for their c
    float2 v0 = __half22float2(*(__half2*)&us.x);
    float2 v1 = __half22float2(*(__half2*)&us.y);
    float2 v2 = __half22float2(*(__half2*)&us.z);
    float2 v3 = __half22float2(*(__half2*)&us.w);
    float h[8];
    h[0] = fmaxf(fmaf(fmaf(v0.x, dd, a0), dd, b1a.x), 0.f);
    h[1] = fmaxf(fmaf(fmaf(v0.y, dd, a1), dd, b1a.y), 0.f);
    h[2] = fmaxf(fmaf(fmaf(v1.x, dd, a2), dd, b1a.z), 0.f);
    h[3] = fmaxf(fmaf(fmaf(v1.y, dd, a3), dd, b1a.w), 0.f);
    h[4] = fmaxf(fmaf(fmaf(v2.x, dd, a4), dd, b1b.x), 0.f);
    h[5] = fmaxf(fmaf(fmaf(v2.y, dd, a5), dd, b1b.y), 0.f);
    h[6] = fmaxf(fmaf(fmaf(v3.x, dd, a6), dd, b1b.z), 0.f);
    h[7] = fmaxf(fmaf(fmaf(v3.y, dd, a7), dd, b1b.w), 0.f);
    float o0 = 0.f, o1 = 0.f;
#pragma unroll
    for (int k = 0; k < 8; ++k) {
        o0 += h[k] * Wcs[(c * 8 + k) * 2 + 0];
        o1 += h[k] * Wcs[(c * 8 + k) * 2 + 1];
    }
#pragma unroll
    for (int off = 1; off < L; off <<= 1) {
        o0 += __shfl_xor(o0, off);
        o1 += __shfl_xor(o1, off);
    }
    if (lane == 0) {
        float2 r; r.x = o0 * dd; r.y = o1 * dd;
        *(float2*)(z + (size_t)node * 2) = r;
    }
}

// ---------------- Layer-2 aggregation on z (2 floats/node) + bias + leaky ----------------
__global__ __launch_bounds__(256) void k_agg2(const int* __restrict__ row_ptr,
                                              const unsigned short* __restrict__ degu,
                                              const unsigned short* __restrict__ csr_src,
                                              const float* __restrict__ dinv,
                                              const float* __restrict__ z,
                                              const float* __restrict__ bc,
                                              float* __restrict__ out, int N) {
    int tid = threadIdx.x;
    int gwave = (blockIdx.x * 256 + tid) >> 6;
    int lane = tid & 63;
    int grp = lane >> 3, li = lane & 7;
    int node = gwave * 8 + grp;
    if (node >= N) return;
    int beg = row_ptr[node];
    int end = beg + degu[node];
    float s0 = 0.f, s1 = 0.f;
    int j = beg + li;
    for (; j + 8 < end; j += 16) {
        int sa = csr_src[j];
        int sb = csr_src[j + 8];
        float2 za = *(const float2*)(z + (size_t)sa * 2);
        float2 zb = *(const float2*)(z + (size_t)sb * 2);
        s0 += za.x + zb.x; s1 += za.y + zb.y;
    }
    if (j < end) {
        int s = csr_src[j];
        float2 zv = *(const float2*)(z + (size_t)s * 2);
        s0 += zv.x; s1 += zv.y;
    }
#pragma unroll
    for (int off = 1; off < 8; off <<= 1) {
        s0 += __shfl_xor(s0, off);
        s1 += __shfl_xor(s1, off);
    }
    if (li == 0) {
        float2 zs = *(const float2*)(z + (size_t)node * 2);
        float dd = dinv[node];
        float o0 = (s0 + zs.x) * dd + bc[0];
        float o1 = (s1 + zs.y) * dd + bc[1];
        float2 r;
        r.x = o0 > 0.f ? o0 : 0.01f * o0;
        r.y = o1 > 0.f ? o1 : 0.01f * o1;
        *(float2*)(out + (size_t)node * 2) = r;
    }
}

extern "C" void kernel_launch(void* const* d_in, const int* in_sizes, int n_in,
                              void* d_out, int out_size, void* d_ws, size_t ws_size,
                              hipStream_t stream) {
    const float* x   = (const float*)d_in[0];
    const int*   ei  = (const int*)d_in[1];
    const float* W1  = (const float*)d_in[2];
    const float* b1  = (const float*)d_in[3];
    const float* W2  = (const float*)d_in[4];
    const float* b2  = (const float*)d_in[5];
    const float* Wfc = (const float*)d_in[6];
    const float* bfc = (const float*)d_in[7];

    const int N = in_sizes[0] / IN_DIM;   // 50000
    const int E = in_sizes[1] / 2;        // 800000
    const int* src = ei;
    const int* dst = ei + E;
    const int nbin = (N + BINW - 1) / BINW;  // 391

    // Workspace layout (256B-aligned regions):
    char* base = (char*)d_ws;
    size_t off = 0;
    auto take = [&](size_t bytes) { size_t o = off; off = (off + bytes + 255) & ~(size_t)255; return (void*)(base + o); };
    int*    row_ptr  = (int*)take((size_t)N * 4);
    unsigned short* degu = (unsigned short*)take((size_t)N * 2);
    unsigned short* csr_src = (unsigned short*)take((size_t)nbin * CAP * 2);
    int*    bin_cnt  = (int*)take((size_t)(nbin * CNTSTRIDE + CNTSTRIDE) * 4);  // + ovf_cnt line
    int*    ovf_cnt  = bin_cnt + nbin * CNTSTRIDE;
    unsigned int* ovf = (unsigned int*)take((size_t)E * 4);     // worst-case, never dropped
    unsigned int* ebin = (unsigned int*)take((size_t)nbin * CAP * 4);
    float*  dinv     = (float*)take((size_t)N * 4);
    __half* xw1h     = (__half*)take((size_t)N * HID_DIM * 2);
    float*  zbuf     = (float*)take((size_t)N * 2 * 4);
    float*  Wc       = (float*)take((size_t)HID_DIM * 2 * 4);
    float*  bc       = (float*)take(2 * 4);

    // zero the padded counters (one line each) + overflow counter
    hipMemsetAsync(bin_cnt, 0, (size_t)(nbin * CNTSTRIDE + CNTSTRIDE) * 4, stream);

    // Fused K1: gemm1 tiles (blocks [0,nGemm)) + scatter (blocks [nGemm,nGemm+256)).
    // gemm no longer needs dinv (scaling deferred to k_agg1z) -> independent of build.
    const int nGemm = (N + 127) / 128;
    k_build_gemm<<<nGemm + SC_GRID, 256, 0, stream>>>(x, W1, xw1h, src, dst, bin_cnt,
                                                      ovf_cnt, ovf, ebin, N, E, nbin);
    // build pass 2 (depends on scatter only)
    k_fill<<<nbin, 256, 0, stream>>>(ebin, bin_cnt, ovf_cnt, ovf, row_ptr, degu,
                                     csr_src, dinv, W2, Wfc, b2, bfc, Wc, bc, N, nbin);
    // Layer-1 aggregation (per-edge dinv[s] weight) + relu + folded 128x2 GEMV -> z
    k_agg1z<<<(N + 3) / 4, 256, 0, stream>>>(row_ptr, degu, csr_src, dinv, xw1h, b1, Wc, zbuf, N);
    // Layer-2 aggregation on z + bias + leaky -> out
    const int nAgg2 = ((N + 7) / 8 * 64 + 255) / 256;
    k_agg2<<<nAgg2, 256, 0, stream>>>(row_ptr, degu, csr_src, dinv, zbuf, bc, (float*)d_out, N);
}

// Round 2
// 156.038 us; speedup vs baseline: 1.1447x; 1.0558x over previous
//
#include <hip/hip_runtime.h>
#include <hip/hip_fp16.h>

// Problem constants (from reference): N=50000, E=800000, dims 128->128->64->2.
#define IN_DIM 128
#define HID_DIM 128
#define OUT_DIM 64
#define BINW 128          // nodes per bin (dst >> 7)
#define BINSHIFT 7
#define MAXBIN 512        // LDS bound; nbin = ceil(N/128) = 391 for N=50000
#define CAP 4096          // fixed bin capacity (mean 2046; overflow handled correctly)
#define CNTSTRIDE 16      // bin_cnt stride in ints (one 64B line per counter)
#define SC_GRID 256       // scatter sub-grid (logical), fused into k_build_gemm

typedef _Float16 f16x8 __attribute__((ext_vector_type(8)));
typedef float f32x4 __attribute__((ext_vector_type(4)));

// ---------------- fused K1: [MFMA gemm1 tiles | scatter blocks] ----------------
// GEMM path rewritten from fp32 VALU (R1 post-mortem: 45us, VALUBusy 27% ->
// latency-stalled, not issue-bound) to f16 MFMA (16x16x32). x is split
// hi+lo fp16 (2 MFMAs, f32 accum) so accuracy stays ~= the old fp32 path;
// W single fp16 (error ~5e-4 < xwh fp16 storage quantum). Operands swapped
// (mfma(W,x)) so each lane's C/D frag holds 4 consecutive OUTPUT COLS of one
// row -> packed 8B stores. Wt staged transposed in LDS, XOR-swizzled
// (((col&7)<<4)) so ds_read_b128 column-slices are ~conflict-free.
__global__ __launch_bounds__(256) void k_build_gemm(const float* __restrict__ x,
                                                    const float* __restrict__ W,
                                                    __half* __restrict__ xwh,
                                                    const int* __restrict__ src,
                                                    const int* __restrict__ dst,
                                                    int* __restrict__ bin_cnt,   // stride CNTSTRIDE
                                                    int* __restrict__ ovf_cnt,
                                                    unsigned int* __restrict__ ovf,
                                                    unsigned int* __restrict__ ebin,
                                                    int N, int E, int nbin) {
    __shared__ union SMem {
        unsigned int wt_raw[8192];                        // gemm path: Wt f16 [col][k] swizzled, 32KB
        struct { int h[MAXBIN]; int base_s[MAXBIN]; } sc; // scatter path: 4KB
    } smem;
    const int nGemm = (N + 127) >> 7;
    int tid = threadIdx.x;

    if ((int)blockIdx.x < nGemm) {
        // ---------------- GEMM path: xwh = fp16(x @ W1), tile 128x128, MFMA ----------------
        char* wb = (char*)smem.wt_raw;
        // ---- stage Wt[col][k] = fp16(W[k][col]), swizzled: byte ^= ((col&7)<<4) ----
        {
            int kk0 = (tid & 15) * 2;        // even k
            int c8  = (tid >> 4) * 8;        // 8 consecutive cols
#pragma unroll
            for (int i = 0; i < 4; ++i) {
                int kk = i * 32 + kk0;
                const float* w0 = W + (size_t)kk * HID_DIM + c8;
                const float* w1 = w0 + HID_DIM;
                float4 a0 = *(const float4*)w0;
                float4 a1 = *(const float4*)(w0 + 4);
                float4 b0 = *(const float4*)w1;
                float4 b1 = *(const float4*)(w1 + 4);
                float va[8] = {a0.x, a0.y, a0.z, a0.w, a1.x, a1.y, a1.z, a1.w};
                float vb[8] = {b0.x, b0.y, b0.z, b0.w, b1.x, b1.y, b1.z, b1.w};
#pragma unroll
                for (int j = 0; j < 8; ++j) {
                    int col = c8 + j;
                    int byte = (col << 8) + (kk << 1);
                    byte ^= ((col & 7) << 4);
                    *(__half2*)(wb + byte) = __floats2half2_rn(va[j], vb[j]);
                }
            }
        }
        int lane = tid & 63;
        int wv   = tid >> 6;
        int lcol = lane & 15;
        int lk   = (lane >> 4) << 3;          // k sub-offset (elements) within 32-chunk
        int swz  = (lcol & 7) << 4;
        int rb   = blockIdx.x * 128 + wv * 32;
        // x row pointers for the 2 row-frags (B-operand: N-index = lane&15)
        int rows[2];
        const float* xp[2];
#pragma unroll
        for (int r = 0; r < 2; ++r) {
            int row = rb + 16 * r + lcol;
            rows[r] = row;
            if (row > N - 1) row = N - 1;
            xp[r] = x + (size_t)row * IN_DIM + lk;
        }
        f32x4 acc[2][8];
#pragma unroll
        for (int r = 0; r < 2; ++r)
#pragma unroll
            for (int c = 0; c < 8; ++c) acc[r][c] = (f32x4){0.f, 0.f, 0.f, 0.f};

        __syncthreads();

        auto mk = [](float4 f0, float4 f1, f16x8& hi, f16x8& lo) {
            float f[8] = {f0.x, f0.y, f0.z, f0.w, f1.x, f1.y, f1.z, f1.w};
#pragma unroll
            for (int e = 0; e < 8; ++e) {
                _Float16 h = (_Float16)f[e];
                hi[e] = h;
                lo[e] = (_Float16)(f[e] - (float)h);
            }
        };
#pragma unroll
        for (int kc = 0; kc < 4; ++kc) {
            f16x8 xhi[2], xlo[2];
#pragma unroll
            for (int r = 0; r < 2; ++r) {
                float4 f0 = *(const float4*)(xp[r] + kc * 32);
                float4 f1 = *(const float4*)(xp[r] + kc * 32 + 4);
                mk(f0, f1, xhi[r], xlo[r]);
            }
#pragma unroll
            for (int c = 0; c < 8; ++c) {
                int ad = ((c << 12) | (lcol << 8) | ((kc << 6) + (lk << 1))) ^ swz;
                f16x8 wfrag = *(const f16x8*)(wb + ad);
                acc[0][c] = __builtin_amdgcn_mfma_f32_16x16x32_f16(wfrag, xhi[0], acc[0][c], 0, 0, 0);
                acc[0][c] = __builtin_amdgcn_mfma_f32_16x16x32_f16(wfrag, xlo[0], acc[0][c], 0, 0, 0);
                acc[1][c] = __builtin_amdgcn_mfma_f32_16x16x32_f16(wfrag, xhi[1], acc[1][c], 0, 0, 0);
                acc[1][c] = __builtin_amdgcn_mfma_f32_16x16x32_f16(wfrag, xlo[1], acc[1][c], 0, 0, 0);
            }
        }
        // ---- store: lane holds xw[row = rb+16r+lcol][16c + 4*(lane>>4) + 0..3] ----
        int cq = lane >> 4;   // which 4-col quad
#pragma unroll
        for (int r = 0; r < 2; ++r) {
            if (rows[r] < N) {
                uint2* p = (uint2*)(xwh + (size_t)rows[r] * HID_DIM);
#pragma unroll
                for (int c = 0; c < 8; ++c) {
                    union { __half2 h[2]; uint2 u; } pk;
                    pk.h[0] = __floats2half2_rn(acc[r][c].x, acc[r][c].y);
                    pk.h[1] = __floats2half2_rn(acc[r][c].z, acc[r][c].w);
                    p[4 * c + cq] = pk.u;
                }
            }
        }
    } else {
        // ---------------- scatter path: hist + atomic reserve + scatter into bins ----------------
        int sb = blockIdx.x - nGemm;               // logical scatter block in [0, SC_GRID)
        int* h = smem.sc.h;
        int* base_s = smem.sc.base_s;
        for (int k = tid; k < nbin; k += 256) h[k] = 0;
        __syncthreads();
        int per = E / SC_GRID;
        int ebeg = sb * per;
        int eend = (sb + 1 == SC_GRID) ? E : ebeg + per;
        for (int i = ebeg + tid; i < eend; i += 256)
            atomicAdd(&h[dst[i] >> BINSHIFT], 1);
        __syncthreads();
        for (int k = tid; k < nbin; k += 256) {
            int c = h[k];
            base_s[k] = (c > 0) ? atomicAdd(&bin_cnt[k * CNTSTRIDE], c) : 0;
            h[k] = 0;   // reuse as local fill counter
        }
        __syncthreads();
        for (int i = ebeg + tid; i < eend; i += 256) {
            unsigned int s = (unsigned int)src[i];
            unsigned int d = (unsigned int)dst[i];
            int b = (int)(d >> BINSHIFT);
            int pos = base_s[b] + atomicAdd(&h[b], 1);
            unsigned int packed = s | (d << 16);
            if (pos < CAP) ebin[(size_t)b * CAP + pos] = packed;
            else ovf[atomicAdd(ovf_cnt, 1)] = packed;   // ovf sized E: can never drop
        }
    }
}

// ---------------- build pass 2: per-bin fill — row_ptr, deg, dinv, csr_src (u16) ----------------
// Block 0 additionally computes Wc = W2@Wfc and bc = b2@Wfc + bfc.
__global__ __launch_bounds__(256) void k_fill(const unsigned int* __restrict__ ebin,
                                              const int* __restrict__ bin_cnt,
                                              const int* __restrict__ ovf_cnt,
                                              const unsigned int* __restrict__ ovf,
                                              int* __restrict__ row_ptr,
                                              unsigned short* __restrict__ degu,
                                              unsigned short* __restrict__ csr_src,
                                              float* __restrict__ dinv,
                                              const float* __restrict__ W2,
                                              const float* __restrict__ Wfc,
                                              const float* __restrict__ b2,
                                              const float* __restrict__ bfc,
                                              float* __restrict__ Wc,
                                              float* __restrict__ bc,
                                              int N, int nbin) {
    __shared__ int cnt[BINW];
    __shared__ int excl[BINW];
    __shared__ int start[BINW];
    int k = blockIdx.x;
    int node0 = k * BINW;
    int nn = min(BINW, N - node0);
    int t = threadIdx.x;
    if (t < BINW) cnt[t] = 0;
    __syncthreads();
    int cnt_k = min(bin_cnt[k * CNTSTRIDE], CAP);
    const unsigned int* seg = ebin + (size_t)k * CAP;
    for (int i = t; i < cnt_k; i += 256)
        atomicAdd(&cnt[(seg[i] >> 16) & (BINW - 1)], 1);
    int novf = *ovf_cnt;
    for (int i = t; i < novf; i += 256) {
        unsigned int e = ovf[i];
        if ((int)(e >> (16 + BINSHIFT)) == k)
            atomicAdd(&cnt[(e >> 16) & (BINW - 1)], 1);
    }
    __syncthreads();
    if (t < BINW) excl[t] = (t < nn) ? cnt[t] : 0;
    __syncthreads();
    for (int off = 1; off < BINW; off <<= 1) {
        int u = 0;
        if (t < BINW && t >= off) u = excl[t - off];
        __syncthreads();
        if (t < BINW) excl[t] += u;   // inclusive scan
        __syncthreads();
    }
    if (t < nn) {
        int deg = cnt[t];
        int e0 = k * CAP + excl[t] - deg;   // absolute slot in csr_src (bins have holes)
        start[t] = e0;
        row_ptr[node0 + t] = e0;
        degu[node0 + t] = (unsigned short)deg;
        dinv[node0 + t] = rsqrtf((float)deg + 1.0f);
        cnt[t] = 0;                         // reuse as fill counter
    }
    __syncthreads();
    for (int i = t; i < cnt_k; i += 256) {
        unsigned int e = seg[i];
        int dl = (e >> 16) & (BINW - 1);
        int slot = start[dl] + atomicAdd(&cnt[dl], 1);
        csr_src[slot] = (unsigned short)(e & 0xffffu);
    }
    for (int i = t; i < novf; i += 256) {
        unsigned int e = ovf[i];
        if ((int)(e >> (16 + BINSHIFT)) == k) {
            int dl = (e >> 16) & (BINW - 1);
            int slot = start[dl] + atomicAdd(&cnt[dl], 1);
            csr_src[slot] = (unsigned short)(e & 0xffffu);
        }
    }
    // ---- block 0: fold Wc = W2 @ Wfc (128x2), bc = b2 @ Wfc + bfc ----
    if (k == 0) {
        int kk = t >> 1, j = t & 1;
        float acc = 0.f;
#pragma unroll 8
        for (int m = 0; m < OUT_DIM; ++m) acc += W2[kk * OUT_DIM + m] * Wfc[m * 2 + j];
        Wc[kk * 2 + j] = acc;
        if (kk == 0) {
            float b = 0.f;
#pragma unroll 8
            for (int m = 0; m < OUT_DIM; ++m) b += b2[m] * Wfc[m * 2 + j];
            bc[j] = b + bfc[j];
        }
    }
}

// ---------------- Layer-1 aggregation + bias + ReLU + (h1 @ Wc) epilogue ----------------
// xwh is UNSCALED; per-edge weight dinv[s] applied here as FMA (same VALU
// rate as the old add). dinv is 200KB -> L2-resident; 16 lanes/edge read the
// same address -> broadcast load.
// h1 = relu(dinv[d]*(sum_s dinv[s]*xwh[s] + dinv[d]*xwh[d]) + b1)
// z[d] = dinv[d] * (h1 @ Wc).  4x-unrolled gather: 16 outstanding uint4 per wave.
__global__ __launch_bounds__(256) void k_agg1z(const int* __restrict__ row_ptr,
                                               const unsigned short* __restrict__ degu,
                                               const unsigned short* __restrict__ csr_src,
                                               const float* __restrict__ dinv,
                                               const __half* __restrict__ xwh,
                                               const float* __restrict__ b1,
                                               const float* __restrict__ Wc,
                                               float* __restrict__ z, int N) {
    constexpr int F = HID_DIM;
    constexpr int L = F / 8;       // 16 lanes per row, 16B/lane
    constexpr int EPW = 64 / L;    // 4 edge slots per wave
    __shared__ float Wcs[HID_DIM * 2];
    int tid = threadIdx.x;
    if (tid < 64) ((float4*)Wcs)[tid] = ((const float4*)Wc)[tid];
    __syncthreads();
    int node = (blockIdx.x * 256 + tid) >> 6;
    if (node >= N) return;
    int lane = tid & 63;
    int sub = lane / L;
    int c   = lane % L;
    int beg = row_ptr[node];
    int end = beg + degu[node];
    // hoisted loads (overlap with gather)
    float dd = dinv[node];
    uint4 us = *(const uint4*)(xwh + (size_t)node * F + c * 8);
    float4 b1a = *(const float4*)(b1 + c * 8);
    float4 b1b = *(const float4*)(b1 + c * 8 + 4);
    float a0 = 0.f, a1 = 0.f, a2 = 0.f, a3 = 0.f;
    float a4 = 0.f, a5 = 0.f, a6 = 0.f, a7 = 0.f;
    auto acc = [&](uint4 u, float w) {
        float2 v0 = __half22float2(*(__half2*)&u.x);
        float2 v1 = __half22float2(*(__half2*)&u.y);
        float2 v2 = __half22float2(*(__half2*)&u.z);
        float2 v3 = __half22float2(*(__half2*)&u.w);
        a0 = fmaf(v0.x, w, a0); a1 = fmaf(v0.y, w, a1);
        a2 = fmaf(v1.x, w, a2); a3 = fmaf(v1.y, w, a3);
        a4 = fmaf(v2.x, w, a4); a5 = fmaf(v2.y, w, a5);
        a6 = fmaf(v3.x, w, a6); a7 = fmaf(v3.y, w, a7);
    };
    int j = beg + sub;
    for (; j + 3 * EPW < end; j += 4 * EPW) {
        int s0 = csr_src[j];
        int s1 = csr_src[j + EPW];
        int s2 = csr_src[j + 2 * EPW];
        int s3 = csr_src[j + 3 * EPW];
        uint4 u0 = *(const uint4*)(xwh + (size_t)s0 * F + c * 8);
        uint4 u1 = *(const uint4*)(xwh + (size_t)s1 * F + c * 8);
        uint4 u2 = *(const uint4*)(xwh + (size_t)s2 * F + c * 8);
        uint4 u3 = *(const uint4*)(xwh + (size_t)s3 * F + c * 8);
        float w0 = dinv[s0];
        float w1 = dinv[s1];
        float w2 = dinv[s2];
        float w3 = dinv[s3];
        acc(u0, w0); acc(u1, w1); acc(u2, w2); acc(u3, w3);
    }
    for (; j < end; j += EPW) {
        int s = csr_src[j];
        uint4 u = *(const uint4*)(xwh + (size_t)s * F + c * 8);
        acc(u, dinv[s]);
    }
#pragma unroll
    for (int off = L; off < 64; off <<= 1) {
        a0 += __shfl_xor(a0, off); a1 += __shfl_xor(a1, off);
        a2 += __shfl_xor(a2, off); a3 += __shfl_xor(a3, off);
        a4 += __shfl_xor(a4, off); a5 += __shfl_xor(a5, off);
        a6 += __shfl_xor(a6, off); a7 += __shfl_xor(a7, off);
    }
    // all lanes now hold the full column sums for their c
    float2 v0 = __half22float2(*(__half2*)&us.x);
    float2 v1 = __half22float2(*(__half2*)&us.y);
    float2 v2 = __half22float2(*(__half2*)&us.z);
    float2 v3 = __half22float2(*(__half2*)&us.w);
    float h[8];
    h[0] = fmaxf(fmaf(fmaf(v0.x, dd, a0), dd, b1a.x), 0.f);
    h[1] = fmaxf(fmaf(fmaf(v0.y, dd, a1), dd, b1a.y), 0.f);
    h[2] = fmaxf(fmaf(fmaf(v1.x, dd, a2), dd, b1a.z), 0.f);
    h[3] = fmaxf(fmaf(fmaf(v1.y, dd, a3), dd, b1a.w), 0.f);
    h[4] = fmaxf(fmaf(fmaf(v2.x, dd, a4), dd, b1b.x), 0.f);
    h[5] = fmaxf(fmaf(fmaf(v2.y, dd, a5), dd, b1b.y), 0.f);
    h[6] = fmaxf(fmaf(fmaf(v3.x, dd, a6), dd, b1b.z), 0.f);
    h[7] = fmaxf(fmaf(fmaf(v3.y, dd, a7), dd, b1b.w), 0.f);
    float o0 = 0.f, o1 = 0.f;
#pragma unroll
    for (int k = 0; k < 8; ++k) {
        o0 += h[k] * Wcs[(c * 8 + k) * 2 + 0];
        o1 += h[k] * Wcs[(c * 8 + k) * 2 + 1];
    }
#pragma unroll
    for (int off = 1; off < L; off <<= 1) {
        o0 += __shfl_xor(o0, off);
        o1 += __shfl_xor(o1, off);
    }
    if (lane == 0) {
        float2 r; r.x = o0 * dd; r.y = o1 * dd;
        *(float2*)(z + (size_t)node * 2) = r;
    }
}

// ---------------- Layer-2 aggregation on z (2 floats/node) + bias + leaky ----------------
__global__ __launch_bounds__(256) void k_agg2(const int* __restrict__ row_ptr,
                                              const unsigned short* __restrict__ degu,
                                              const unsigned short* __restrict__ csr_src,
                                              const float* __restrict__ dinv,
                                              const float* __restrict__ z,
                                              const float* __restrict__ bc,
                                              float* __restrict__ out, int N) {
    int tid = threadIdx.x;
    int gwave = (blockIdx.x * 256 + tid) >> 6;
    int lane = tid & 63;
    int grp = lane >> 3, li = lane & 7;
    int node = gwave * 8 + grp;
    if (node >= N) return;
    int beg = row_ptr[node];
    int end = beg + degu[node];
    float s0 = 0.f, s1 = 0.f;
    int j = beg + li;
    for (; j + 8 < end; j += 16) {
        int sa = csr_src[j];
        int sb = csr_src[j + 8];
        float2 za = *(const float2*)(z + (size_t)sa * 2);
        float2 zb = *(const float2*)(z + (size_t)sb * 2);
        s0 += za.x + zb.x; s1 += za.y + zb.y;
    }
    if (j < end) {
        int s = csr_src[j];
        float2 zv = *(const float2*)(z + (size_t)s * 2);
        s0 += zv.x; s1 += zv.y;
    }
#pragma unroll
    for (int off = 1; off < 8; off <<= 1) {
        s0 += __shfl_xor(s0, off);
        s1 += __shfl_xor(s1, off);
    }
    if (li == 0) {
        float2 zs = *(const float2*)(z + (size_t)node * 2);
        float dd = dinv[node];
        float o0 = (s0 + zs.x) * dd + bc[0];
        float o1 = (s1 + zs.y) * dd + bc[1];
        float2 r;
        r.x = o0 > 0.f ? o0 : 0.01f * o0;
        r.y = o1 > 0.f ? o1 : 0.01f * o1;
        *(float2*)(out + (size_t)node * 2) = r;
    }
}

extern "C" void kernel_launch(void* const* d_in, const int* in_sizes, int n_in,
                              void* d_out, int out_size, void* d_ws, size_t ws_size,
                              hipStream_t stream) {
    const float* x   = (const float*)d_in[0];
    const int*   ei  = (const int*)d_in[1];
    const float* W1  = (const float*)d_in[2];
    const float* b1  = (const float*)d_in[3];
    const float* W2  = (const float*)d_in[4];
    const float* b2  = (const float*)d_in[5];
    const float* Wfc = (const float*)d_in[6];
    const float* bfc = (const float*)d_in[7];

    const int N = in_sizes[0] / IN_DIM;   // 50000
    const int E = in_sizes[1] / 2;        // 800000
    const int* src = ei;
    const int* dst = ei + E;
    const int nbin = (N + BINW - 1) / BINW;  // 391

    // Workspace layout (256B-aligned regions):
    char* base = (char*)d_ws;
    size_t off = 0;
    auto take = [&](size_t bytes) { size_t o = off; off = (off + bytes + 255) & ~(size_t)255; return (void*)(base + o); };
    int*    row_ptr  = (int*)take((size_t)N * 4);
    unsigned short* degu = (unsigned short*)take((size_t)N * 2);
    unsigned short* csr_src = (unsigned short*)take((size_t)nbin * CAP * 2);
    int*    bin_cnt  = (int*)take((size_t)(nbin * CNTSTRIDE + CNTSTRIDE) * 4);  // + ovf_cnt line
    int*    ovf_cnt  = bin_cnt + nbin * CNTSTRIDE;
    unsigned int* ovf = (unsigned int*)take((size_t)E * 4);     // worst-case, never dropped
    unsigned int* ebin = (unsigned int*)take((size_t)nbin * CAP * 4);
    float*  dinv     = (float*)take((size_t)N * 4);
    __half* xw1h     = (__half*)take((size_t)N * HID_DIM * 2);
    float*  zbuf     = (float*)take((size_t)N * 2 * 4);
    float*  Wc       = (float*)take((size_t)HID_DIM * 2 * 4);
    float*  bc       = (float*)take(2 * 4);

    // zero the padded counters (one line each) + overflow counter
    hipMemsetAsync(bin_cnt, 0, (size_t)(nbin * CNTSTRIDE + CNTSTRIDE) * 4, stream);

    // Fused K1: MFMA gemm1 tiles (blocks [0,nGemm)) + scatter (blocks [nGemm,nGemm+256)).
    const int nGemm = (N + 127) / 128;
    k_build_gemm<<<nGemm + SC_GRID, 256, 0, stream>>>(x, W1, xw1h, src, dst, bin_cnt,
                                                      ovf_cnt, ovf, ebin, N, E, nbin);
    // build pass 2 (depends on scatter only)
    k_fill<<<nbin, 256, 0, stream>>>(ebin, bin_cnt, ovf_cnt, ovf, row_ptr, degu,
                                     csr_src, dinv, W2, Wfc, b2, bfc, Wc, bc, N, nbin);
    // Layer-1 aggregation (per-edge dinv[s] weight) + relu + folded 128x2 GEMV -> z
    k_agg1z<<<(N + 3) / 4, 256, 0, stream>>>(row_ptr, degu, csr_src, dinv, xw1h, b1, Wc, zbuf, N);
    // Layer-2 aggregation on z + bias + leaky -> out
    const int nAgg2 = ((N + 7) / 8 * 64 + 255) / 256;
    k_agg2<<<nAgg2, 256, 0, stream>>>(row_ptr, degu, csr_src, dinv, zbuf, bc, (float*)d_out, N);
}

// Round 3
// 153.595 us; speedup vs baseline: 1.1629x; 1.0159x over previous
//
#include <hip/hip_runtime.h>
#include <hip/hip_fp16.h>

// Problem constants (from reference): N=50000, E=800000, dims 128->128->64->2.
#define IN_DIM 128
#define HID_DIM 128
#define OUT_DIM 64
#define BINW 128          // nodes per bin (dst >> 7)
#define BINSHIFT 7
#define MAXBIN 512        // LDS bound; nbin = ceil(N/128) = 391 for N=50000
#define CAP 4096          // fixed bin capacity (mean 2046; overflow handled correctly)
#define CNTSTRIDE 16      // bin_cnt stride in ints (one 64B line per counter)
#define SC_GRID 256       // scatter sub-grid (logical), fused into k_build_gemm
#define SBUF 3456         // per-block edge slots for local sort (E/SC_GRID + remainder)

typedef _Float16 f16x8 __attribute__((ext_vector_type(8)));
typedef float f32x4 __attribute__((ext_vector_type(4)));

// ---------------- fused K1: [MFMA gemm1 tiles | scatter blocks] ----------------
// R2 post-mortem: scatter (~36us) is K1's long pole, not the MFMA gemm (~10us).
// Scatter rewritten as block-local counting sort: hist -> block scan -> rank
// into sorted LDS buffer -> coalesced bin-grouped global writes. This kills
// the 16x line amplification of random 4B ebin stores.
__global__ __launch_bounds__(256) void k_build_gemm(const float* __restrict__ x,
                                                    const float* __restrict__ W,
                                                    __half* __restrict__ xwh,
                                                    const int* __restrict__ src,
                                                    const int* __restrict__ dst,
                                                    int* __restrict__ bin_cnt,   // stride CNTSTRIDE
                                                    int* __restrict__ ovf_cnt,
                                                    unsigned int* __restrict__ ovf,
                                                    unsigned int* __restrict__ ebin,
                                                    int N, int E, int nbin) {
    __shared__ union SMem {
        unsigned int wt_raw[8192];                        // gemm path: Wt f16 [col][k] swizzled, 32KB
        struct {                                          // scatter path: ~21KB
            int h[MAXBIN];
            int excl[MAXBIN];
            int base_s[MAXBIN];
            int ps[256];
            unsigned int sortbuf[SBUF];
        } sc;
    } smem;
    const int nGemm = (N + 127) >> 7;
    int tid = threadIdx.x;

    if ((int)blockIdx.x < nGemm) {
        // ---------------- GEMM path: xwh = fp16(x @ W1), tile 128x128, MFMA ----------------
        char* wb = (char*)smem.wt_raw;
        // ---- stage Wt[col][k] = fp16(W[k][col]), swizzled: byte ^= ((col&7)<<4) ----
        {
            int kk0 = (tid & 15) * 2;        // even k
            int c8  = (tid >> 4) * 8;        // 8 consecutive cols
#pragma unroll
            for (int i = 0; i < 4; ++i) {
                int kk = i * 32 + kk0;
                const float* w0 = W + (size_t)kk * HID_DIM + c8;
                const float* w1 = w0 + HID_DIM;
                float4 a0 = *(const float4*)w0;
                float4 a1 = *(const float4*)(w0 + 4);
                float4 b0 = *(const float4*)w1;
                float4 b1 = *(const float4*)(w1 + 4);
                float va[8] = {a0.x, a0.y, a0.z, a0.w, a1.x, a1.y, a1.z, a1.w};
                float vb[8] = {b0.x, b0.y, b0.z, b0.w, b1.x, b1.y, b1.z, b1.w};
#pragma unroll
                for (int j = 0; j < 8; ++j) {
                    int col = c8 + j;
                    int byte = (col << 8) + (kk << 1);
                    byte ^= ((col & 7) << 4);
                    *(__half2*)(wb + byte) = __floats2half2_rn(va[j], vb[j]);
                }
            }
        }
        int lane = tid & 63;
        int wv   = tid >> 6;
        int lcol = lane & 15;
        int lk   = (lane >> 4) << 3;          // k sub-offset (elements) within 32-chunk
        int swz  = (lcol & 7) << 4;
        int rb   = blockIdx.x * 128 + wv * 32;
        // x row pointers for the 2 row-frags (B-operand: N-index = lane&15)
        int rows[2];
        const float* xp[2];
#pragma unroll
        for (int r = 0; r < 2; ++r) {
            int row = rb + 16 * r + lcol;
            rows[r] = row;
            if (row > N - 1) row = N - 1;
            xp[r] = x + (size_t)row * IN_DIM + lk;
        }
        f32x4 acc[2][8];
#pragma unroll
        for (int r = 0; r < 2; ++r)
#pragma unroll
            for (int c = 0; c < 8; ++c) acc[r][c] = (f32x4){0.f, 0.f, 0.f, 0.f};

        __syncthreads();

        auto mk = [](float4 f0, float4 f1, f16x8& hi, f16x8& lo) {
            float f[8] = {f0.x, f0.y, f0.z, f0.w, f1.x, f1.y, f1.z, f1.w};
#pragma unroll
            for (int e = 0; e < 8; ++e) {
                _Float16 h = (_Float16)f[e];
                hi[e] = h;
                lo[e] = (_Float16)(f[e] - (float)h);
            }
        };
#pragma unroll
        for (int kc = 0; kc < 4; ++kc) {
            f16x8 xhi[2], xlo[2];
#pragma unroll
            for (int r = 0; r < 2; ++r) {
                float4 f0 = *(const float4*)(xp[r] + kc * 32);
                float4 f1 = *(const float4*)(xp[r] + kc * 32 + 4);
                mk(f0, f1, xhi[r], xlo[r]);
            }
#pragma unroll
            for (int c = 0; c < 8; ++c) {
                int ad = ((c << 12) | (lcol << 8) | ((kc << 6) + (lk << 1))) ^ swz;
                f16x8 wfrag = *(const f16x8*)(wb + ad);
                acc[0][c] = __builtin_amdgcn_mfma_f32_16x16x32_f16(wfrag, xhi[0], acc[0][c], 0, 0, 0);
                acc[0][c] = __builtin_amdgcn_mfma_f32_16x16x32_f16(wfrag, xlo[0], acc[0][c], 0, 0, 0);
                acc[1][c] = __builtin_amdgcn_mfma_f32_16x16x32_f16(wfrag, xhi[1], acc[1][c], 0, 0, 0);
                acc[1][c] = __builtin_amdgcn_mfma_f32_16x16x32_f16(wfrag, xlo[1], acc[1][c], 0, 0, 0);
            }
        }
        // ---- store: lane holds xw[row = rb+16r+lcol][16c + 4*(lane>>4) + 0..3] ----
        int cq = lane >> 4;   // which 4-col quad
#pragma unroll
        for (int r = 0; r < 2; ++r) {
            if (rows[r] < N) {
                uint2* p = (uint2*)(xwh + (size_t)rows[r] * HID_DIM);
#pragma unroll
                for (int c = 0; c < 8; ++c) {
                    union { __half2 h[2]; uint2 u; } pk;
                    pk.h[0] = __floats2half2_rn(acc[r][c].x, acc[r][c].y);
                    pk.h[1] = __floats2half2_rn(acc[r][c].z, acc[r][c].w);
                    p[4 * c + cq] = pk.u;
                }
            }
        }
    } else {
        // ---------------- scatter path: local counting sort + coalesced bin writes ----------------
        int sb = blockIdx.x - nGemm;               // logical scatter block in [0, SC_GRID)
        int* h = smem.sc.h;
        int* excl = smem.sc.excl;
        int* base_s = smem.sc.base_s;
        int* ps = smem.sc.ps;
        unsigned int* sortbuf = smem.sc.sortbuf;
        for (int k = tid; k < MAXBIN; k += 256) h[k] = 0;
        __syncthreads();
        int per = E / SC_GRID;
        int ebeg = sb * per;
        int eend = (sb + 1 == SC_GRID) ? E : ebeg + per;
        // pass 1: histogram
        for (int i = ebeg + tid; i < eend; i += 256)
            atomicAdd(&h[dst[i] >> BINSHIFT], 1);
        __syncthreads();
        // block-wide exclusive scan over 512 bins (pair-sum + Hillis-Steele on 256)
        int b0 = 2 * tid, b1 = 2 * tid + 1;
        int c0 = h[b0], c1 = h[b1];
        ps[tid] = c0 + c1;
        __syncthreads();
        for (int off = 1; off < 256; off <<= 1) {
            int v = (tid >= off) ? ps[tid - off] : 0;
            __syncthreads();
            ps[tid] += v;
            __syncthreads();
        }
        int Pprev = (tid > 0) ? ps[tid - 1] : 0;
        excl[b0] = Pprev;
        excl[b1] = Pprev + c0;
        __syncthreads();
        // pass 2: global reserve; reset h as rank counter
        for (int k = tid; k < nbin; k += 256) {
            int c = h[k];
            base_s[k] = (c > 0) ? atomicAdd(&bin_cnt[k * CNTSTRIDE], c) : 0;
            h[k] = 0;
        }
        __syncthreads();
        // pass 3: rank into sorted LDS buffer (grouped by bin)
        for (int i = ebeg + tid; i < eend; i += 256) {
            unsigned int s = (unsigned int)src[i];
            unsigned int d = (unsigned int)dst[i];
            int b = (int)(d >> BINSHIFT);
            int r = atomicAdd(&h[b], 1);
            sortbuf[excl[b] + r] = s | (d << 16);
        }
        __syncthreads();
        // pass 4: coalesced write of bin-grouped runs
        int tot = eend - ebeg;
        for (int i = tid; i < tot; i += 256) {
            unsigned int p = sortbuf[i];
            int b = (int)(p >> (16 + BINSHIFT));
            int g = base_s[b] + (i - excl[b]);
            if (g < CAP) ebin[(size_t)b * CAP + g] = p;
            else ovf[atomicAdd(ovf_cnt, 1)] = p;   // ovf sized E: can never drop
        }
    }
}

// ---------------- build pass 2: per-bin fill — row_ptr, deg, dinv, csr_src (u16) ----------------
// Block 0 additionally computes Wc = W2@Wfc and bc = b2@Wfc + bfc.
__global__ __launch_bounds__(256) void k_fill(const unsigned int* __restrict__ ebin,
                                              const int* __restrict__ bin_cnt,
                                              const int* __restrict__ ovf_cnt,
                                              const unsigned int* __restrict__ ovf,
                                              int* __restrict__ row_ptr,
                                              unsigned short* __restrict__ degu,
                                              unsigned short* __restrict__ csr_src,
                                              float* __restrict__ dinv,
                                              const float* __restrict__ W2,
                                              const float* __restrict__ Wfc,
                                              const float* __restrict__ b2,
                                              const float* __restrict__ bfc,
                                              float* __restrict__ Wc,
                                              float* __restrict__ bc,
                                              int N, int nbin) {
    __shared__ int cnt[BINW];
    __shared__ int excl[BINW];
    __shared__ int start[BINW];
    int k = blockIdx.x;
    int node0 = k * BINW;
    int nn = min(BINW, N - node0);
    int t = threadIdx.x;
    if (t < BINW) cnt[t] = 0;
    __syncthreads();
    int cnt_k = min(bin_cnt[k * CNTSTRIDE], CAP);
    const unsigned int* seg = ebin + (size_t)k * CAP;
    for (int i = t; i < cnt_k; i += 256)
        atomicAdd(&cnt[(seg[i] >> 16) & (BINW - 1)], 1);
    int novf = *ovf_cnt;
    for (int i = t; i < novf; i += 256) {
        unsigned int e = ovf[i];
        if ((int)(e >> (16 + BINSHIFT)) == k)
            atomicAdd(&cnt[(e >> 16) & (BINW - 1)], 1);
    }
    __syncthreads();
    if (t < BINW) excl[t] = (t < nn) ? cnt[t] : 0;
    __syncthreads();
    for (int off = 1; off < BINW; off <<= 1) {
        int u = 0;
        if (t < BINW && t >= off) u = excl[t - off];
        __syncthreads();
        if (t < BINW) excl[t] += u;   // inclusive scan
        __syncthreads();
    }
    if (t < nn) {
        int deg = cnt[t];
        int e0 = k * CAP + excl[t] - deg;   // absolute slot in csr_src (bins have holes)
        start[t] = e0;
        row_ptr[node0 + t] = e0;
        degu[node0 + t] = (unsigned short)deg;
        dinv[node0 + t] = rsqrtf((float)deg + 1.0f);
        cnt[t] = 0;                         // reuse as fill counter
    }
    __syncthreads();
    for (int i = t; i < cnt_k; i += 256) {
        unsigned int e = seg[i];
        int dl = (e >> 16) & (BINW - 1);
        int slot = start[dl] + atomicAdd(&cnt[dl], 1);
        csr_src[slot] = (unsigned short)(e & 0xffffu);
    }
    for (int i = t; i < novf; i += 256) {
        unsigned int e = ovf[i];
        if ((int)(e >> (16 + BINSHIFT)) == k) {
            int dl = (e >> 16) & (BINW - 1);
            int slot = start[dl] + atomicAdd(&cnt[dl], 1);
            csr_src[slot] = (unsigned short)(e & 0xffffu);
        }
    }
    // ---- block 0: fold Wc = W2 @ Wfc (128x2), bc = b2 @ Wfc + bfc ----
    if (k == 0) {
        int kk = t >> 1, j = t & 1;
        float acc = 0.f;
#pragma unroll 8
        for (int m = 0; m < OUT_DIM; ++m) acc += W2[kk * OUT_DIM + m] * Wfc[m * 2 + j];
        Wc[kk * 2 + j] = acc;
        if (kk == 0) {
            float b = 0.f;
#pragma unroll 8
            for (int m = 0; m < OUT_DIM; ++m) b += b2[m] * Wfc[m * 2 + j];
            bc[j] = b + bfc[j];
        }
    }
}

// ---------------- Layer-1 aggregation + bias + ReLU + (h1 @ Wc) epilogue ----------------
// xwh is UNSCALED; per-edge weight dinv[s] applied here as FMA.
// h1 = relu(dinv[d]*(sum_s dinv[s]*xwh[s] + dinv[d]*xwh[d]) + b1)
// z[d] = dinv[d] * (h1 @ Wc).  4x-unrolled gather: 16 outstanding uint4 per wave.
__global__ __launch_bounds__(256) void k_agg1z(const int* __restrict__ row_ptr,
                                               const unsigned short* __restrict__ degu,
                                               const unsigned short* __restrict__ csr_src,
                                               const float* __restrict__ dinv,
                                               const __half* __restrict__ xwh,
                                               const float* __restrict__ b1,
                                               const float* __restrict__ Wc,
                                               float* __restrict__ z, int N) {
    constexpr int F = HID_DIM;
    constexpr int L = F / 8;       // 16 lanes per row, 16B/lane
    constexpr int EPW = 64 / L;    // 4 edge slots per wave
    __shared__ float Wcs[HID_DIM * 2];
    int tid = threadIdx.x;
    if (tid < 64) ((float4*)Wcs)[tid] = ((const float4*)Wc)[tid];
    __syncthreads();
    int node = (blockIdx.x * 256 + tid) >> 6;
    if (node >= N) return;
    int lane = tid & 63;
    int sub = lane / L;
    int c   = lane % L;
    int beg = row_ptr[node];
    int end = beg + degu[node];
    // hoisted loads (overlap with gather)
    float dd = dinv[node];
    uint4 us = *(const uint4*)(xwh + (size_t)node * F + c * 8);
    float4 b1a = *(const float4*)(b1 + c * 8);
    float4 b1b = *(const float4*)(b1 + c * 8 + 4);
    float a0 = 0.f, a1 = 0.f, a2 = 0.f, a3 = 0.f;
    float a4 = 0.f, a5 = 0.f, a6 = 0.f, a7 = 0.f;
    auto acc = [&](uint4 u, float w) {
        float2 v0 = __half22float2(*(__half2*)&u.x);
        float2 v1 = __half22float2(*(__half2*)&u.y);
        float2 v2 = __half22float2(*(__half2*)&u.z);
        float2 v3 = __half22float2(*(__half2*)&u.w);
        a0 = fmaf(v0.x, w, a0); a1 = fmaf(v0.y, w, a1);
        a2 = fmaf(v1.x, w, a2); a3 = fmaf(v1.y, w, a3);
        a4 = fmaf(v2.x, w, a4); a5 = fmaf(v2.y, w, a5);
        a6 = fmaf(v3.x, w, a6); a7 = fmaf(v3.y, w, a7);
    };
    int j = beg + sub;
    for (; j + 3 * EPW < end; j += 4 * EPW) {
        int s0 = csr_src[j];
        int s1 = csr_src[j + EPW];
        int s2 = csr_src[j + 2 * EPW];
        int s3 = csr_src[j + 3 * EPW];
        uint4 u0 = *(const uint4*)(xwh + (size_t)s0 * F + c * 8);
        uint4 u1 = *(const uint4*)(xwh + (size_t)s1 * F + c * 8);
        uint4 u2 = *(const uint4*)(xwh + (size_t)s2 * F + c * 8);
        uint4 u3 = *(const uint4*)(xwh + (size_t)s3 * F + c * 8);
        float w0 = dinv[s0];
        float w1 = dinv[s1];
        float w2 = dinv[s2];
        float w3 = dinv[s3];
        acc(u0, w0); acc(u1, w1); acc(u2, w2); acc(u3, w3);
    }
    for (; j < end; j += EPW) {
        int s = csr_src[j];
        uint4 u = *(const uint4*)(xwh + (size_t)s * F + c * 8);
        acc(u, dinv[s]);
    }
#pragma unroll
    for (int off = L; off < 64; off <<= 1) {
        a0 += __shfl_xor(a0, off); a1 += __shfl_xor(a1, off);
        a2 += __shfl_xor(a2, off); a3 += __shfl_xor(a3, off);
        a4 += __shfl_xor(a4, off); a5 += __shfl_xor(a5, off);
        a6 += __shfl_xor(a6, off); a7 += __shfl_xor(a7, off);
    }
    // all lanes now hold the full column sums for their c
    float2 v0 = __half22float2(*(__half2*)&us.x);
    float2 v1 = __half22float2(*(__half2*)&us.y);
    float2 v2 = __half22float2(*(__half2*)&us.z);
    float2 v3 = __half22float2(*(__half2*)&us.w);
    float h[8];
    h[0] = fmaxf(fmaf(fmaf(v0.x, dd, a0), dd, b1a.x), 0.f);
    h[1] = fmaxf(fmaf(fmaf(v0.y, dd, a1), dd, b1a.y), 0.f);
    h[2] = fmaxf(fmaf(fmaf(v1.x, dd, a2), dd, b1a.z), 0.f);
    h[3] = fmaxf(fmaf(fmaf(v1.y, dd, a3), dd, b1a.w), 0.f);
    h[4] = fmaxf(fmaf(fmaf(v2.x, dd, a4), dd, b1b.x), 0.f);
    h[5] = fmaxf(fmaf(fmaf(v2.y, dd, a5), dd, b1b.y), 0.f);
    h[6] = fmaxf(fmaf(fmaf(v3.x, dd, a6), dd, b1b.z), 0.f);
    h[7] = fmaxf(fmaf(fmaf(v3.y, dd, a7), dd, b1b.w), 0.f);
    float o0 = 0.f, o1 = 0.f;
#pragma unroll
    for (int k = 0; k < 8; ++k) {
        o0 += h[k] * Wcs[(c * 8 + k) * 2 + 0];
        o1 += h[k] * Wcs[(c * 8 + k) * 2 + 1];
    }
#pragma unroll
    for (int off = 1; off < L; off <<= 1) {
        o0 += __shfl_xor(o0, off);
        o1 += __shfl_xor(o1, off);
    }
    if (lane == 0) {
        float2 r; r.x = o0 * dd; r.y = o1 * dd;
        *(float2*)(z + (size_t)node * 2) = r;
    }
}

// ---------------- Layer-2 aggregation on z (2 floats/node) + bias + leaky ----------------
__global__ __launch_bounds__(256) void k_agg2(const int* __restrict__ row_ptr,
                                              const unsigned short* __restrict__ degu,
                                              const unsigned short* __restrict__ csr_src,
                                              const float* __restrict__ dinv,
                                              const float* __restrict__ z,
                                              const float* __restrict__ bc,
                                              float* __restrict__ out, int N) {
    int tid = threadIdx.x;
    int gwave = (blockIdx.x * 256 + tid) >> 6;
    int lane = tid & 63;
    int grp = lane >> 3, li = lane & 7;
    int node = gwave * 8 + grp;
    if (node >= N) return;
    int beg = row_ptr[node];
    int end = beg + degu[node];
    float s0 = 0.f, s1 = 0.f;
    int j = beg + li;
    for (; j + 8 < end; j += 16) {
        int sa = csr_src[j];
        int sb = csr_src[j + 8];
        float2 za = *(const float2*)(z + (size_t)sa * 2);
        float2 zb = *(const float2*)(z + (size_t)sb * 2);
        s0 += za.x + zb.x; s1 += za.y + zb.y;
    }
    if (j < end) {
        int s = csr_src[j];
        float2 zv = *(const float2*)(z + (size_t)s * 2);
        s0 += zv.x; s1 += zv.y;
    }
#pragma unroll
    for (int off = 1; off < 8; off <<= 1) {
        s0 += __shfl_xor(s0, off);
        s1 += __shfl_xor(s1, off);
    }
    if (li == 0) {
        float2 zs = *(const float2*)(z + (size_t)node * 2);
        float dd = dinv[node];
        float o0 = (s0 + zs.x) * dd + bc[0];
        float o1 = (s1 + zs.y) * dd + bc[1];
        float2 r;
        r.x = o0 > 0.f ? o0 : 0.01f * o0;
        r.y = o1 > 0.f ? o1 : 0.01f * o1;
        *(float2*)(out + (size_t)node * 2) = r;
    }
}

extern "C" void kernel_launch(void* const* d_in, const int* in_sizes, int n_in,
                              void* d_out, int out_size, void* d_ws, size_t ws_size,
                              hipStream_t stream) {
    const float* x   = (const float*)d_in[0];
    const int*   ei  = (const int*)d_in[1];
    const float* W1  = (const float*)d_in[2];
    const float* b1  = (const float*)d_in[3];
    const float* W2  = (const float*)d_in[4];
    const float* b2  = (const float*)d_in[5];
    const float* Wfc = (const float*)d_in[6];
    const float* bfc = (const float*)d_in[7];

    const int N = in_sizes[0] / IN_DIM;   // 50000
    const int E = in_sizes[1] / 2;        // 800000
    const int* src = ei;
    const int* dst = ei + E;
    const int nbin = (N + BINW - 1) / BINW;  // 391

    // Workspace layout (256B-aligned regions):
    char* base = (char*)d_ws;
    size_t off = 0;
    auto take = [&](size_t bytes) { size_t o = off; off = (off + bytes + 255) & ~(size_t)255; return (void*)(base + o); };
    int*    row_ptr  = (int*)take((size_t)N * 4);
    unsigned short* degu = (unsigned short*)take((size_t)N * 2);
    unsigned short* csr_src = (unsigned short*)take((size_t)nbin * CAP * 2);
    int*    bin_cnt  = (int*)take((size_t)(nbin * CNTSTRIDE + CNTSTRIDE) * 4);  // + ovf_cnt line
    int*    ovf_cnt  = bin_cnt + nbin * CNTSTRIDE;
    unsigned int* ovf = (unsigned int*)take((size_t)E * 4);     // worst-case, never dropped
    unsigned int* ebin = (unsigned int*)take((size_t)nbin * CAP * 4);
    float*  dinv     = (float*)take((size_t)N * 4);
    __half* xw1h     = (__half*)take((size_t)N * HID_DIM * 2);
    float*  zbuf     = (float*)take((size_t)N * 2 * 4);
    float*  Wc       = (float*)take((size_t)HID_DIM * 2 * 4);
    float*  bc       = (float*)take(2 * 4);

    // zero the padded counters (one line each) + overflow counter
    hipMemsetAsync(bin_cnt, 0, (size_t)(nbin * CNTSTRIDE + CNTSTRIDE) * 4, stream);

    // Fused K1: MFMA gemm1 tiles (blocks [0,nGemm)) + scatter (blocks [nGemm,nGemm+256)).
    const int nGemm = (N + 127) / 128;
    k_build_gemm<<<nGemm + SC_GRID, 256, 0, stream>>>(x, W1, xw1h, src, dst, bin_cnt,
                                                      ovf_cnt, ovf, ebin, N, E, nbin);
    // build pass 2 (depends on scatter only)
    k_fill<<<nbin, 256, 0, stream>>>(ebin, bin_cnt, ovf_cnt, ovf, row_ptr, degu,
                                     csr_src, dinv, W2, Wfc, b2, bfc, Wc, bc, N, nbin);
    // Layer-1 aggregation (per-edge dinv[s] weight) + relu + folded 128x2 GEMV -> z
    k_agg1z<<<(N + 3) / 4, 256, 0, stream>>>(row_ptr, degu, csr_src, dinv, xw1h, b1, Wc, zbuf, N);
    // Layer-2 aggregation on z + bias + leaky -> out
    const int nAgg2 = ((N + 7) / 8 * 64 + 255) / 256;
    k_agg2<<<nAgg2, 256, 0, stream>>>(row_ptr, degu, csr_src, dinv, zbuf, bc, (float*)d_out, N);
}